// Round 14
// baseline (308.178 us; speedup 1.0000x reference)
//
#include <hip/hip_runtime.h>
#include <stdint.h>

#define B_ 2
#define S_ 2048
#define D_ 1024
#define H_ 16
#define HD_ 64
#define NT_ (S_ / 64)
// SCALE * log2(e): softmax computed in exp2 domain
#define SC2_ 0.18033688011112042f

typedef __bf16 bf16_t;
typedef bf16_t bf16x8 __attribute__((ext_vector_type(8)));
typedef float f32x4 __attribute__((ext_vector_type(4)));
typedef unsigned short u16x8 __attribute__((ext_vector_type(8)));
typedef unsigned short u16x4 __attribute__((ext_vector_type(4)));

static __device__ __forceinline__ unsigned short f2b(float f) {
  return __builtin_bit_cast(unsigned short, (bf16_t)f);   // native cvt (RNE)
}

static __device__ __forceinline__ bf16x8 asb(u16x8 u) {
  return __builtin_bit_cast(bf16x8, u);
}

// ---------------- cast fp32 -> bf16, fused launches ----------------
__global__ void cast3(const float* __restrict__ a, const float* __restrict__ b,
                      const float* __restrict__ c,
                      unsigned short* __restrict__ dst, int n) {
  const float* src = blockIdx.y == 0 ? a : (blockIdx.y == 1 ? b : c);
  unsigned short* d = dst + (size_t)blockIdx.y * n;
  int i = (blockIdx.x * blockDim.x + threadIdx.x) * 8;
  if (i >= n) return;
  float4 f0 = *(const float4*)(src + i);
  float4 f1 = *(const float4*)(src + i + 4);
  u16x8 o;
  o[0] = f2b(f0.x); o[1] = f2b(f0.y); o[2] = f2b(f0.z); o[3] = f2b(f0.w);
  o[4] = f2b(f1.x); o[5] = f2b(f1.y); o[6] = f2b(f1.z); o[7] = f2b(f1.w);
  *(u16x8*)(d + i) = o;
}

__global__ void cast4(const float* __restrict__ a, const float* __restrict__ b,
                      const float* __restrict__ c, const float* __restrict__ e,
                      unsigned short* __restrict__ dst, int n) {
  const float* src = blockIdx.y == 0 ? a
                   : (blockIdx.y == 1 ? b : (blockIdx.y == 2 ? c : e));
  unsigned short* d = dst + (size_t)blockIdx.y * n;
  int i = (blockIdx.x * blockDim.x + threadIdx.x) * 8;
  if (i >= n) return;
  float4 f0 = *(const float4*)(src + i);
  float4 f1 = *(const float4*)(src + i + 4);
  u16x8 o;
  o[0] = f2b(f0.x); o[1] = f2b(f0.y); o[2] = f2b(f0.z); o[3] = f2b(f0.w);
  o[4] = f2b(f1.x); o[5] = f2b(f1.y); o[6] = f2b(f1.z); o[7] = f2b(f1.w);
  *(u16x8*)(d + i) = o;
}

// ---------------- pack mask to bits via ballot ----------------
__global__ void pack_mask(const int* __restrict__ mask,
                          uint32_t* __restrict__ mbits) {
  int i = blockIdx.x * blockDim.x + threadIdx.x;
  unsigned long long bits = __ballot(mask[i] != 0);
  if ((threadIdx.x & 63) == 0)
    *(unsigned long long*)&mbits[i >> 5] = bits;
}

// ---------------- bf16 GEMM (r2 structure): C = A[M,K] @ W[N,K]^T + bias ----
// Reg-staged + one-K-step prefetch + padded-40 LDS (proven best: r10 vs r12).
// OUTMODE 0: z=0,1 -> bf16 head-split [B,H,S,HD]; z=2 -> bf16 V^T [B,H,HD,S].
// OUTMODE 1: fp32 row-major [M,N] (non-temporal: never re-read).
template<int OUTMODE>
__global__ __launch_bounds__(256)
void gemm_bt(const unsigned short* __restrict__ Ab,
             const unsigned short* __restrict__ Wb,
             const float* __restrict__ bq_,
             const float* __restrict__ bk_,
             const float* __restrict__ bv_,
             void* __restrict__ outv,
             int M, int N, int K) {
  const int z = blockIdx.z;
  const unsigned short* A = Ab + (size_t)z * M * K;
  const unsigned short* W = Wb + (size_t)z * N * K;
  const float* bias = z == 0 ? bq_ : (z == 1 ? bk_ : bv_);

  // padded stride 40 u16 = 80B (5 mod 8 -> 2-way bank spread on b128 reads)
  __shared__ __align__(16) unsigned short As[128 * 40];
  __shared__ __align__(16) unsigned short Bs[128 * 40];

  const int tid = threadIdx.x;
  const int lane = tid & 63;
  const int wave = tid >> 6;
  const int wm = wave >> 1, wn = wave & 1;
  const int row0 = blockIdx.x * 128;
  const int col0 = blockIdx.y * 128;

  const int srow = tid >> 2;        // 0..63
  const int scol = (tid & 3) * 8;   // 0,8,16,24
  const int lr = lane & 15;
  const int lg = lane >> 4;
  const int lk = lg * 8;

  f32x4 acc[4][4] = {};

  u16x8 a0 = *(const u16x8*)&A[(size_t)(row0 + srow) * K + scol];
  u16x8 a1 = *(const u16x8*)&A[(size_t)(row0 + srow + 64) * K + scol];
  u16x8 b0 = *(const u16x8*)&W[(size_t)(col0 + srow) * K + scol];
  u16x8 b1 = *(const u16x8*)&W[(size_t)(col0 + srow + 64) * K + scol];

  for (int k0 = 0; k0 < K; k0 += 32) {
    __syncthreads();   // prior iteration's LDS reads complete
    *(u16x8*)&As[srow * 40 + scol] = a0;
    *(u16x8*)&As[(srow + 64) * 40 + scol] = a1;
    *(u16x8*)&Bs[srow * 40 + scol] = b0;
    *(u16x8*)&Bs[(srow + 64) * 40 + scol] = b1;
    if (k0 + 32 < K) {
      a0 = *(const u16x8*)&A[(size_t)(row0 + srow) * K + k0 + 32 + scol];
      a1 = *(const u16x8*)&A[(size_t)(row0 + srow + 64) * K + k0 + 32 + scol];
      b0 = *(const u16x8*)&W[(size_t)(col0 + srow) * K + k0 + 32 + scol];
      b1 = *(const u16x8*)&W[(size_t)(col0 + srow + 64) * K + k0 + 32 + scol];
    }
    __syncthreads();

    bf16x8 af[4], bfr[4];
#pragma unroll
    for (int i = 0; i < 4; ++i)
      af[i] = asb(*(const u16x8*)&As[(wm * 64 + i * 16 + lr) * 40 + lk]);
#pragma unroll
    for (int j = 0; j < 4; ++j)
      bfr[j] = asb(*(const u16x8*)&Bs[(wn * 64 + j * 16 + lr) * 40 + lk]);
#pragma unroll
    for (int i = 0; i < 4; ++i)
#pragma unroll
      for (int j = 0; j < 4; ++j)
        acc[i][j] = __builtin_amdgcn_mfma_f32_16x16x32_bf16(af[i], bfr[j], acc[i][j], 0, 0, 0);
  }

  const size_t zo = (size_t)z * M * N;
#pragma unroll
  for (int i = 0; i < 4; ++i) {
#pragma unroll
    for (int j = 0; j < 4; ++j) {
      const int row_ = row0 + wm * 64 + i * 16 + lg * 4;
      const int col = col0 + wn * 64 + j * 16 + lr;
      const float bcol = bias[col];
      if (OUTMODE == 1) {
        float* O = (float*)outv;
#pragma unroll
        for (int r = 0; r < 4; ++r)
          __builtin_nontemporal_store(acc[i][j][r] + bcol,
                                      &O[(size_t)(row_ + r) * N + col]);
      } else if (z == 2) {
        // V^T: [bh][hd][s], 4 consecutive s per lane -> 8B store
        unsigned short* O = (unsigned short*)outv + zo;
        int b = row_ >> 11, s = row_ & 2047;
        int h = col >> 6, hd = col & 63;
        u16x4 pk;
#pragma unroll
        for (int r = 0; r < 4; ++r) pk[r] = f2b(acc[i][j][r] + bcol);
        *(u16x4*)&O[(((size_t)b * H_ + h) * HD_ + hd) * S_ + s] = pk;
      } else {
        unsigned short* O = (unsigned short*)outv + zo;
        int h = col >> 6, hd = col & 63;
#pragma unroll
        for (int r = 0; r < 4; ++r) {
          int row = row_ + r;
          int b = row >> 11, s = row & 2047;
          O[(((size_t)b * H_ + h) * S_ + s) * HD_ + hd] = f2b(acc[i][j][r] + bcol);
        }
      }
    }
  }
}

// XCD-aware remap for grid (16,32) = 512 blocks: each XCD owns 4 consecutive
// bh values (K+V+Q ~ 3MB < 4MB L2) across its 16 q-tiles.
static __device__ __forceinline__ void xcd_map(int& bh, int& qt) {
  int lin = blockIdx.y * 16 + blockIdx.x;
  int xcd = lin & 7, k = lin >> 3;          // 64 blocks per XCD
  bh = (xcd << 2) | (k >> 4);               // 4 heads per XCD
  qt = k & 15;
}

// ---------------- fused attention, 1024 threads ------------------------------
// 128 q-rows per block, 16 waves = 8 wq x 2 wk (sk-halves). Staging of K (and
// V in loop 2) split across thread-halves: waves 0-7 stage K, waves 8-15 stage
// V -> per-q-row staging traffic, global K/V refetch and barrier count HALVE
// vs the 64q/512thr r13 layout, at equal occupancy (2 blocks x 16 waves/CU).
// Loop 1: per-row (m2,l); merge via LDS; loop 2: normalized weights + PV.
__global__ __launch_bounds__(1024, 8)
void attn_fused(const unsigned short* __restrict__ q_bh,
                const unsigned short* __restrict__ k_bh,
                const unsigned short* __restrict__ vt_g,
                const uint32_t* __restrict__ mbits,
                float* __restrict__ w_out,
                unsigned short* __restrict__ attn_out) {
  int bh, qt;
  xcd_map(bh, qt);
  const int b = bh >> 4, h = bh & (H_ - 1);
  const int q0 = qt * 128;

  __shared__ __align__(16) unsigned char smem[36864];
  unsigned short* Ks = (unsigned short*)smem;        // [64*72]   9216B
  unsigned short* Vs = Ks + 64 * 72;                 // [64*72]   9216B
  unsigned short* Ps = Vs + 64 * 72;                 // 16x[16*36] 18432B
  float* cs = (float*)smem;                          // end-overlay, 34816B
  float2* mls = (float2*)Ps;                         // merge overlay, 2KB

  const int tid = threadIdx.x, lane = tid & 63, w = tid >> 6;   // w 0..15
  const int wq = w >> 1, wk = w & 1;                            // wq 0..7
  const int sthalf = tid >> 9;                                  // 0:K 1:V
  const int st = tid & 511;
  const int srow = st >> 3, scol = (st & 7) * 8;                // 64 x 64
  const int lr = lane & 15, lg = lane >> 4, lk = lg * 8;
  const int sq = q0 + wq * 16 + lr;
  unsigned short* Psw = Ps + w * (16 * 36);

  const unsigned short* qb = q_bh + ((size_t)bh * S_ + sq) * HD_;
  bf16x8 qf0 = asb(*(const u16x8*)&qb[lk]);
  bf16x8 qf1 = asb(*(const u16x8*)&qb[32 + lk]);

  const uint32_t* mrow = mbits + ((size_t)b * S_ + sq) * (S_ / 32);
  const unsigned short* kb = k_bh + (size_t)bh * S_ * HD_;
  const unsigned short* vb = vt_g + (size_t)bh * HD_ * S_;

  // ---------------- loop 1: per-row (m2, l) over this wave's sk-half -------
  float m2 = -__builtin_inff(), l = 0.f;
  {
    u16x8 t0;
    if (sthalf == 0) t0 = *(const u16x8*)&kb[srow * 64 + scol];
    for (int kt = 0; kt < NT_; ++kt) {
      __syncthreads();
      if (sthalf == 0) {
        *(u16x8*)&Ks[srow * 72 + scol] = t0;
        if (kt + 1 < NT_)
          t0 = *(const u16x8*)&kb[((kt + 1) * 64 + srow) * 64 + scol];
      }
      __syncthreads();

      uint32_t mw = mrow[kt * 2 + wk];
      const bool full = __all(mw == 0xffffffffu);

      f32x4 sa[2] = {};
#pragma unroll
      for (int jj = 0; jj < 2; ++jj) {
        const int j = wk * 2 + jj;
        bf16x8 kf0 = asb(*(const u16x8*)&Ks[(j * 16 + lr) * 72 + lk]);
        bf16x8 kf1 = asb(*(const u16x8*)&Ks[(j * 16 + lr) * 72 + 32 + lk]);
        sa[jj] = __builtin_amdgcn_mfma_f32_16x16x32_bf16(kf0, qf0, sa[jj], 0, 0, 0);
        sa[jj] = __builtin_amdgcn_mfma_f32_16x16x32_bf16(kf1, qf1, sa[jj], 0, 0, 0);
      }

      float sv[2][4];
      if (full) {
#pragma unroll
        for (int jj = 0; jj < 2; ++jj)
#pragma unroll
          for (int r = 0; r < 4; ++r) sv[jj][r] = sa[jj][r] * SC2_;
      } else {
#pragma unroll
        for (int jj = 0; jj < 2; ++jj)
#pragma unroll
          for (int r = 0; r < 4; ++r) {
            int bit = jj * 16 + lg * 4 + r;
            sv[jj][r] = ((mw >> bit) & 1) ? sa[jj][r] * SC2_ : -3.0e9f;
          }
      }
      float tm = sv[0][0];
#pragma unroll
      for (int jj = 0; jj < 2; ++jj)
#pragma unroll
        for (int r = 0; r < 4; ++r) tm = fmaxf(tm, sv[jj][r]);
      tm = fmaxf(tm, __shfl_xor(tm, 16));
      tm = fmaxf(tm, __shfl_xor(tm, 32));
      float mnew = fmaxf(m2, tm);
      float ss = 0.f;
#pragma unroll
      for (int jj = 0; jj < 2; ++jj)
#pragma unroll
        for (int r = 0; r < 4; ++r)
          ss += __builtin_amdgcn_exp2f(sv[jj][r] - mnew);
      ss += __shfl_xor(ss, 16);
      ss += __shfl_xor(ss, 32);
      l = l * __builtin_amdgcn_exp2f(m2 - mnew) + ss;
      m2 = mnew;
    }
  }

  // ---------------- merge sk-halves: all lanes get full-row (m, l) ---------
  __syncthreads();                        // Ks reads done; Ps idle -> overlay
  if (lg == 0) mls[wk * 128 + wq * 16 + lr] = make_float2(m2, l);
  __syncthreads();
  float2 h0 = mls[wq * 16 + lr];
  float2 h1 = mls[128 + wq * 16 + lr];
  const float mn = fmaxf(h0.x, h1.x);
  const float lsum = h0.y * __builtin_amdgcn_exp2f(h0.x - mn) +
                     h1.y * __builtin_amdgcn_exp2f(h1.x - mn);
  // p = exp2(sa*SC2 + off), off = -m - log2(l)  (normalization folded in)
  const float off = -mn - __builtin_amdgcn_logf(lsum);
  float* wrow = w_out + ((size_t)bh * S_ + sq) * S_;

  // ---------------- loop 2: weights write + PV ------------------------------
  u16x8 s0;
  if (sthalf == 0) s0 = *(const u16x8*)&kb[srow * 64 + scol];
  else             s0 = *(const u16x8*)&vb[(size_t)srow * S_ + scol];

  f32x4 oacc[4] = {};

  for (int kt = 0; kt < NT_; ++kt) {
    const int k0 = kt * 64;
    __syncthreads();   // prior iteration's QK/PV LDS reads (or mls reads) done
    if (sthalf == 0) *(u16x8*)&Ks[srow * 72 + scol] = s0;
    else             *(u16x8*)&Vs[srow * 72 + scol] = s0;
    if (kt + 1 < NT_) {
      if (sthalf == 0) s0 = *(const u16x8*)&kb[(k0 + 64 + srow) * 64 + scol];
      else             s0 = *(const u16x8*)&vb[(size_t)srow * S_ + k0 + 64 + scol];
    }
    __syncthreads();

    uint32_t mw = mrow[kt * 2 + wk];
    const bool full = __all(mw == 0xffffffffu);

    f32x4 sa[2] = {};
#pragma unroll
    for (int jj = 0; jj < 2; ++jj) {
      const int j = wk * 2 + jj;
      bf16x8 kf0 = asb(*(const u16x8*)&Ks[(j * 16 + lr) * 72 + lk]);
      bf16x8 kf1 = asb(*(const u16x8*)&Ks[(j * 16 + lr) * 72 + 32 + lk]);
      sa[jj] = __builtin_amdgcn_mfma_f32_16x16x32_bf16(kf0, qf0, sa[jj], 0, 0, 0);
      sa[jj] = __builtin_amdgcn_mfma_f32_16x16x32_bf16(kf1, qf1, sa[jj], 0, 0, 0);
    }

    // weights: lane owns row sq; sk = k0 + wk*32 + jj*16 + lg*4 + r
#pragma unroll
    for (int jj = 0; jj < 2; ++jj) {
      f32x4 pv;
      u16x4 pb;
      if (full) {
#pragma unroll
        for (int r = 0; r < 4; ++r) {
          float p = __builtin_amdgcn_exp2f(fmaf(sa[jj][r], SC2_, off));
          pv[r] = p;
          pb[r] = f2b(p);
        }
      } else {
#pragma unroll
        for (int r = 0; r < 4; ++r) {
          int bit = jj * 16 + lg * 4 + r;
          float x = ((mw >> bit) & 1) ? fmaf(sa[jj][r], SC2_, off) : -3.0e9f;
          float p = __builtin_amdgcn_exp2f(x);
          pv[r] = p;
          pb[r] = f2b(p);
        }
      }
      // streaming store: bypass L2 so K/V stay resident
      __builtin_nontemporal_store(pv,
          (f32x4*)&wrow[k0 + wk * 32 + jj * 16 + lg * 4]);
      *(u16x4*)&Psw[lr * 36 + jj * 16 + lg * 4] = pb;   // wave-local 32 cols
    }

    // PV over this wave's 32-sk slice: A = P (row=sq), B = V^T (col=hd)
    bf16x8 pa = asb(*(const u16x8*)&Psw[lr * 36 + lk]);
#pragma unroll
    for (int j2 = 0; j2 < 4; ++j2) {
      bf16x8 vf = asb(*(const u16x8*)&Vs[(j2 * 16 + lr) * 72 + wk * 32 + lk]);
      oacc[j2] = __builtin_amdgcn_mfma_f32_16x16x32_bf16(pa, vf, oacc[j2], 0, 0, 0);
    }
  }

  // combine sk-half partials: wave (wq,1) -> LDS, wave (wq,0) adds + stores
  __syncthreads();                      // all tile LDS reads done; overlay safe
  const int ci = (wq * 64 + lane) * 17; // 17-dword stride: conflict-free
  if (wk == 1) {
#pragma unroll
    for (int j2 = 0; j2 < 4; ++j2)
#pragma unroll
      for (int r = 0; r < 4; ++r) cs[ci + j2 * 4 + r] = oacc[j2][r];
  }
  __syncthreads();
  if (wk == 0) {
    // D: col = hd = j2*16+lr, row = sq-local = lg*4+r
#pragma unroll
    for (int j2 = 0; j2 < 4; ++j2)
#pragma unroll
      for (int r = 0; r < 4; ++r) {
        float v = oacc[j2][r] + cs[ci + j2 * 4 + r];
        attn_out[((size_t)b * S_ + q0 + wq * 16 + lg * 4 + r) * D_ + h * HD_ + j2 * 16 + lr] =
            f2b(v);
      }
  }
}

// ---------------- launch ----------------
extern "C" void kernel_launch(void* const* d_in, const int* in_sizes, int n_in,
                              void* d_out, int out_size, void* d_ws, size_t ws_size,
                              hipStream_t stream) {
  const float* query = (const float*)d_in[0];
  const float* key   = (const float*)d_in[1];
  const float* value = (const float*)d_in[2];
  const int*   mask  = (const int*)d_in[3];
  const float* Wq = (const float*)d_in[4];
  const float* bq = (const float*)d_in[5];
  const float* Wk = (const float*)d_in[6];
  const float* bk = (const float*)d_in[7];
  const float* Wv = (const float*)d_in[8];
  const float* bv = (const float*)d_in[9];
  const float* Wo = (const float*)d_in[10];
  const float* bo = (const float*)d_in[11];

  const int NE = B_ * S_ * D_;   // 4194304
  const int NW = D_ * D_;        // 1048576

  char* ws = (char*)d_ws;
  unsigned short* xin  = (unsigned short*)(ws);              // 3*NE bf16, dead after proj
  uint32_t*       mbits = (uint32_t*)(ws + 8388608);         // 1MB, inside dead xin
  unsigned short* wbuf = (unsigned short*)(ws + 25165824);   // 4*NW bf16
  unsigned short* qkv  = (unsigned short*)(ws + 33554432);   // 3*NE bf16 (v stored ^T)
  unsigned short* aout = (unsigned short*)(ws + 59244544);   // NE bf16

  cast3<<<dim3(NE / 2048, 3), dim3(256), 0, stream>>>(query, key, value, xin, NE);
  cast4<<<dim3(NW / 2048, 4), dim3(256), 0, stream>>>(Wq, Wk, Wv, Wo, wbuf, NW);

  // q,k,v projections (z = 0,1,2); z==2 writes V transposed per head
  gemm_bt<0><<<dim3(32, 8, 3), dim3(256), 0, stream>>>(
      xin, wbuf, bq, bk, bv, qkv, 4096, 1024, 1024);

  // xin dead now: build mask bits there
  pack_mask<<<dim3(B_ * S_ * S_ / 256), dim3(256), 0, stream>>>(mask, mbits);

  float* w_out = (float*)d_out + NE;   // attn_weights region
  attn_fused<<<dim3(16, 32), dim3(1024), 0, stream>>>(
      qkv, qkv + NE, qkv + 2 * NE, mbits, w_out, aout);

  // output projection -> fp32 d_out
  gemm_bt<1><<<dim3(32, 8, 1), dim3(256), 0, stream>>>(
      aout, wbuf + 3 * NW, bo, bo, bo, d_out, 4096, 1024, 1024);
}

// Round 15
// 282.655 us; speedup vs baseline: 1.0903x; 1.0903x over previous
//
#include <hip/hip_runtime.h>
#include <stdint.h>

#define B_ 2
#define S_ 2048
#define D_ 1024
#define H_ 16
#define HD_ 64
#define NT_ (S_ / 64)
// SCALE * log2(e): softmax computed in exp2 domain
#define SC2_ 0.18033688011112042f

typedef __bf16 bf16_t;
typedef bf16_t bf16x8 __attribute__((ext_vector_type(8)));
typedef float f32x4 __attribute__((ext_vector_type(4)));
typedef unsigned short u16x8 __attribute__((ext_vector_type(8)));
typedef unsigned short u16x4 __attribute__((ext_vector_type(4)));

static __device__ __forceinline__ unsigned short f2b(float f) {
  return __builtin_bit_cast(unsigned short, (bf16_t)f);   // native cvt (RNE)
}

static __device__ __forceinline__ bf16x8 asb(u16x8 u) {
  return __builtin_bit_cast(bf16x8, u);
}

// ---------------- cast fp32 -> bf16, fused launches ----------------
__global__ void cast3(const float* __restrict__ a, const float* __restrict__ b,
                      const float* __restrict__ c,
                      unsigned short* __restrict__ dst, int n) {
  const float* src = blockIdx.y == 0 ? a : (blockIdx.y == 1 ? b : c);
  unsigned short* d = dst + (size_t)blockIdx.y * n;
  int i = (blockIdx.x * blockDim.x + threadIdx.x) * 8;
  if (i >= n) return;
  float4 f0 = *(const float4*)(src + i);
  float4 f1 = *(const float4*)(src + i + 4);
  u16x8 o;
  o[0] = f2b(f0.x); o[1] = f2b(f0.y); o[2] = f2b(f0.z); o[3] = f2b(f0.w);
  o[4] = f2b(f1.x); o[5] = f2b(f1.y); o[6] = f2b(f1.z); o[7] = f2b(f1.w);
  *(u16x8*)(d + i) = o;
}

__global__ void cast4(const float* __restrict__ a, const float* __restrict__ b,
                      const float* __restrict__ c, const float* __restrict__ e,
                      unsigned short* __restrict__ dst, int n) {
  const float* src = blockIdx.y == 0 ? a
                   : (blockIdx.y == 1 ? b : (blockIdx.y == 2 ? c : e));
  unsigned short* d = dst + (size_t)blockIdx.y * n;
  int i = (blockIdx.x * blockDim.x + threadIdx.x) * 8;
  if (i >= n) return;
  float4 f0 = *(const float4*)(src + i);
  float4 f1 = *(const float4*)(src + i + 4);
  u16x8 o;
  o[0] = f2b(f0.x); o[1] = f2b(f0.y); o[2] = f2b(f0.z); o[3] = f2b(f0.w);
  o[4] = f2b(f1.x); o[5] = f2b(f1.y); o[6] = f2b(f1.z); o[7] = f2b(f1.w);
  *(u16x8*)(d + i) = o;
}

// ---------------- pack mask to bits via ballot ----------------
__global__ void pack_mask(const int* __restrict__ mask,
                          uint32_t* __restrict__ mbits) {
  int i = blockIdx.x * blockDim.x + threadIdx.x;
  unsigned long long bits = __ballot(mask[i] != 0);
  if ((threadIdx.x & 63) == 0)
    *(unsigned long long*)&mbits[i >> 5] = bits;
}

// ---------------- bf16 GEMM (r2 structure): C = A[M,K] @ W[N,K]^T + bias ----
// Reg-staged + one-K-step prefetch + padded-40 LDS (proven best: r10 vs r12).
// OUTMODE 0: z=0,1 -> bf16 head-split [B,H,S,HD]; z=2 -> bf16 V^T [B,H,HD,S].
// OUTMODE 1: fp32 row-major [M,N] (non-temporal: never re-read).
template<int OUTMODE>
__global__ __launch_bounds__(256)
void gemm_bt(const unsigned short* __restrict__ Ab,
             const unsigned short* __restrict__ Wb,
             const float* __restrict__ bq_,
             const float* __restrict__ bk_,
             const float* __restrict__ bv_,
             void* __restrict__ outv,
             int M, int N, int K) {
  const int z = blockIdx.z;
  const unsigned short* A = Ab + (size_t)z * M * K;
  const unsigned short* W = Wb + (size_t)z * N * K;
  const float* bias = z == 0 ? bq_ : (z == 1 ? bk_ : bv_);

  // padded stride 40 u16 = 80B (5 mod 8 -> 2-way bank spread on b128 reads)
  __shared__ __align__(16) unsigned short As[128 * 40];
  __shared__ __align__(16) unsigned short Bs[128 * 40];

  const int tid = threadIdx.x;
  const int lane = tid & 63;
  const int wave = tid >> 6;
  const int wm = wave >> 1, wn = wave & 1;
  const int row0 = blockIdx.x * 128;
  const int col0 = blockIdx.y * 128;

  const int srow = tid >> 2;        // 0..63
  const int scol = (tid & 3) * 8;   // 0,8,16,24
  const int lr = lane & 15;
  const int lg = lane >> 4;
  const int lk = lg * 8;

  f32x4 acc[4][4] = {};

  u16x8 a0 = *(const u16x8*)&A[(size_t)(row0 + srow) * K + scol];
  u16x8 a1 = *(const u16x8*)&A[(size_t)(row0 + srow + 64) * K + scol];
  u16x8 b0 = *(const u16x8*)&W[(size_t)(col0 + srow) * K + scol];
  u16x8 b1 = *(const u16x8*)&W[(size_t)(col0 + srow + 64) * K + scol];

  for (int k0 = 0; k0 < K; k0 += 32) {
    __syncthreads();   // prior iteration's LDS reads complete
    *(u16x8*)&As[srow * 40 + scol] = a0;
    *(u16x8*)&As[(srow + 64) * 40 + scol] = a1;
    *(u16x8*)&Bs[srow * 40 + scol] = b0;
    *(u16x8*)&Bs[(srow + 64) * 40 + scol] = b1;
    if (k0 + 32 < K) {
      a0 = *(const u16x8*)&A[(size_t)(row0 + srow) * K + k0 + 32 + scol];
      a1 = *(const u16x8*)&A[(size_t)(row0 + srow + 64) * K + k0 + 32 + scol];
      b0 = *(const u16x8*)&W[(size_t)(col0 + srow) * K + k0 + 32 + scol];
      b1 = *(const u16x8*)&W[(size_t)(col0 + srow + 64) * K + k0 + 32 + scol];
    }
    __syncthreads();

    bf16x8 af[4], bfr[4];
#pragma unroll
    for (int i = 0; i < 4; ++i)
      af[i] = asb(*(const u16x8*)&As[(wm * 64 + i * 16 + lr) * 40 + lk]);
#pragma unroll
    for (int j = 0; j < 4; ++j)
      bfr[j] = asb(*(const u16x8*)&Bs[(wn * 64 + j * 16 + lr) * 40 + lk]);
#pragma unroll
    for (int i = 0; i < 4; ++i)
#pragma unroll
      for (int j = 0; j < 4; ++j)
        acc[i][j] = __builtin_amdgcn_mfma_f32_16x16x32_bf16(af[i], bfr[j], acc[i][j], 0, 0, 0);
  }

  const size_t zo = (size_t)z * M * N;
#pragma unroll
  for (int i = 0; i < 4; ++i) {
#pragma unroll
    for (int j = 0; j < 4; ++j) {
      const int row_ = row0 + wm * 64 + i * 16 + lg * 4;
      const int col = col0 + wn * 64 + j * 16 + lr;
      const float bcol = bias[col];
      if (OUTMODE == 1) {
        float* O = (float*)outv;
#pragma unroll
        for (int r = 0; r < 4; ++r)
          __builtin_nontemporal_store(acc[i][j][r] + bcol,
                                      &O[(size_t)(row_ + r) * N + col]);
      } else if (z == 2) {
        // V^T: [bh][hd][s], 4 consecutive s per lane -> 8B store
        unsigned short* O = (unsigned short*)outv + zo;
        int b = row_ >> 11, s = row_ & 2047;
        int h = col >> 6, hd = col & 63;
        u16x4 pk;
#pragma unroll
        for (int r = 0; r < 4; ++r) pk[r] = f2b(acc[i][j][r] + bcol);
        *(u16x4*)&O[(((size_t)b * H_ + h) * HD_ + hd) * S_ + s] = pk;
      } else {
        unsigned short* O = (unsigned short*)outv + zo;
        int h = col >> 6, hd = col & 63;
#pragma unroll
        for (int r = 0; r < 4; ++r) {
          int row = row_ + r;
          int b = row >> 11, s = row & 2047;
          O[(((size_t)b * H_ + h) * S_ + s) * HD_ + hd] = f2b(acc[i][j][r] + bcol);
        }
      }
    }
  }
}

// XCD-aware remap for grid (32,32): each XCD owns 4 consecutive bh values so
// its private L2 keeps those heads' K/V/Q resident across all q-tiles.
static __device__ __forceinline__ void xcd_map(int& bh, int& qt) {
  int lin = blockIdx.y * 32 + blockIdx.x;
  int xcd = lin & 7, k = lin >> 3;          // 128 blocks per XCD
  bh = (xcd << 2) | (k >> 5);               // 4 heads per XCD
  qt = k & 31;
}

// ---------------- fused attention (r13 + 128-wide loop 1) --------------------
// 64 q-rows per block, 8 waves = 4 q-subtiles x 2 sk-halves.
// Loop 1: per-row (m2,l) with KVBLK=128 (K staged into Ks+Vs region; half the
//         barriers of the 64-wide version; wave wk owns 64-row half per tile).
// Merge: 1KB LDS exchange. Loop 2: KVBLK=64 weights write (nt) + PV (r13).
__global__ __launch_bounds__(512)
void attn_fused(const unsigned short* __restrict__ q_bh,
                const unsigned short* __restrict__ k_bh,
                const unsigned short* __restrict__ vt_g,
                const uint32_t* __restrict__ mbits,
                float* __restrict__ w_out,
                unsigned short* __restrict__ attn_out) {
  int bh, qt;
  xcd_map(bh, qt);
  const int b = bh >> 4, h = bh & (H_ - 1);
  const int q0 = qt * 64;

  __shared__ __align__(16) unsigned char smem[36864];
  unsigned short* Ks = (unsigned short*)smem;        // [64*72]  9216B
  unsigned short* Vs = Ks + 64 * 72;                 // [64*72]  9216B
  unsigned short* Kbig = Ks;                         // loop1: [128*72] 18432B
  unsigned short* Ps = Vs + 64 * 72;                 // [8][16*72] 18432B
  float* cs = (float*)smem;                          // end-overlay, 17408B
  float2* mls = (float2*)Ps;                         // merge overlay, 1KB

  const int tid = threadIdx.x, lane = tid & 63, w = tid >> 6;
  const int wq = w >> 1, wk = w & 1;
  const int srow = tid >> 3, scol = (tid & 7) * 8;   // srow 0..63
  const int lr = lane & 15, lg = lane >> 4, lk = lg * 8;
  const int sq = q0 + wq * 16 + lr;
  unsigned short* Psw = Ps + w * (16 * 72);

  const unsigned short* qb = q_bh + ((size_t)bh * S_ + sq) * HD_;
  bf16x8 qf0 = asb(*(const u16x8*)&qb[lk]);
  bf16x8 qf1 = asb(*(const u16x8*)&qb[32 + lk]);

  const uint32_t* mrow = mbits + ((size_t)b * S_ + sq) * (S_ / 32);
  const unsigned short* kb = k_bh + (size_t)bh * S_ * HD_;
  const unsigned short* vb = vt_g + (size_t)bh * HD_ * S_;

  // ------- loop 1: per-row (m2, l); KVBLK=128, wave owns rows wk*64.. -------
  float m2 = -__builtin_inff(), l = 0.f;
  {
    u16x8 t0 = *(const u16x8*)&kb[srow * 64 + scol];
    u16x8 t1 = *(const u16x8*)&kb[(srow + 64) * 64 + scol];
    for (int kt = 0; kt < S_ / 128; ++kt) {
      __syncthreads();
      *(u16x8*)&Kbig[srow * 72 + scol] = t0;
      *(u16x8*)&Kbig[(srow + 64) * 72 + scol] = t1;
      if (kt + 1 < S_ / 128) {
        t0 = *(const u16x8*)&kb[((kt + 1) * 128 + srow) * 64 + scol];
        t1 = *(const u16x8*)&kb[((kt + 1) * 128 + 64 + srow) * 64 + scol];
      }
      __syncthreads();

      uint2 mw = *(const uint2*)&mrow[kt * 4 + wk * 2];
      const bool full = __all((mw.x & mw.y) == 0xffffffffu);

      f32x4 sa[4] = {};
#pragma unroll
      for (int j = 0; j < 4; ++j) {
        const int row = wk * 64 + j * 16 + lr;
        bf16x8 kf0 = asb(*(const u16x8*)&Kbig[row * 72 + lk]);
        bf16x8 kf1 = asb(*(const u16x8*)&Kbig[row * 72 + 32 + lk]);
        sa[j] = __builtin_amdgcn_mfma_f32_16x16x32_bf16(kf0, qf0, sa[j], 0, 0, 0);
        sa[j] = __builtin_amdgcn_mfma_f32_16x16x32_bf16(kf1, qf1, sa[j], 0, 0, 0);
      }

      float sv[4][4];
      if (full) {
#pragma unroll
        for (int j = 0; j < 4; ++j)
#pragma unroll
          for (int r = 0; r < 4; ++r) sv[j][r] = sa[j][r] * SC2_;
      } else {
#pragma unroll
        for (int j = 0; j < 4; ++j) {
          uint32_t mwj = (j < 2) ? mw.x : mw.y;
#pragma unroll
          for (int r = 0; r < 4; ++r) {
            int bit = (j & 1) * 16 + lg * 4 + r;
            sv[j][r] = ((mwj >> bit) & 1) ? sa[j][r] * SC2_ : -3.0e9f;
          }
        }
      }
      float tm = sv[0][0];
#pragma unroll
      for (int j = 0; j < 4; ++j)
#pragma unroll
        for (int r = 0; r < 4; ++r) tm = fmaxf(tm, sv[j][r]);
      tm = fmaxf(tm, __shfl_xor(tm, 16));
      tm = fmaxf(tm, __shfl_xor(tm, 32));
      float mnew = fmaxf(m2, tm);
      float ss = 0.f;
#pragma unroll
      for (int j = 0; j < 4; ++j)
#pragma unroll
        for (int r = 0; r < 4; ++r)
          ss += __builtin_amdgcn_exp2f(sv[j][r] - mnew);
      ss += __shfl_xor(ss, 16);
      ss += __shfl_xor(ss, 32);
      l = l * __builtin_amdgcn_exp2f(m2 - mnew) + ss;
      m2 = mnew;
    }
  }

  // ---------------- merge sk-halves: all lanes get full-row (m, l) ---------
  __syncthreads();                        // Kbig reads done; Ps idle -> overlay
  if (lg == 0) mls[wk * 64 + wq * 16 + lr] = make_float2(m2, l);
  __syncthreads();
  float2 h0 = mls[wq * 16 + lr];
  float2 h1 = mls[64 + wq * 16 + lr];
  const float mn = fmaxf(h0.x, h1.x);
  const float lsum = h0.y * __builtin_amdgcn_exp2f(h0.x - mn) +
                     h1.y * __builtin_amdgcn_exp2f(h1.x - mn);
  // p = exp2(sa*SC2 + off), off = -m - log2(l)  (normalization folded in)
  const float off = -mn - __builtin_amdgcn_logf(lsum);
  float* wrow = w_out + ((size_t)bh * S_ + sq) * S_;

  // ---------------- loop 2: weights write + PV ------------------------------
  u16x8 t0 = *(const u16x8*)&kb[srow * 64 + scol];
  u16x8 v0 = *(const u16x8*)&vb[(size_t)srow * S_ + scol];

  f32x4 oacc[4] = {};

  for (int kt = 0; kt < NT_; ++kt) {
    const int k0 = kt * 64;
    __syncthreads();   // prior iteration's QK/PV LDS reads (or mls reads) done
    *(u16x8*)&Ks[srow * 72 + scol] = t0;
    *(u16x8*)&Vs[srow * 72 + scol] = v0;
    if (kt + 1 < NT_) {
      t0 = *(const u16x8*)&kb[(k0 + 64 + srow) * 64 + scol];
      v0 = *(const u16x8*)&vb[(size_t)srow * S_ + k0 + 64 + scol];
    }
    __syncthreads();

    uint32_t mw = mrow[kt * 2 + wk];
    const bool full = __all(mw == 0xffffffffu);

    f32x4 sa[2] = {};
#pragma unroll
    for (int jj = 0; jj < 2; ++jj) {
      const int j = wk * 2 + jj;
      bf16x8 kf0 = asb(*(const u16x8*)&Ks[(j * 16 + lr) * 72 + lk]);
      bf16x8 kf1 = asb(*(const u16x8*)&Ks[(j * 16 + lr) * 72 + 32 + lk]);
      sa[jj] = __builtin_amdgcn_mfma_f32_16x16x32_bf16(kf0, qf0, sa[jj], 0, 0, 0);
      sa[jj] = __builtin_amdgcn_mfma_f32_16x16x32_bf16(kf1, qf1, sa[jj], 0, 0, 0);
    }

    // weights: lane owns row sq; sk = k0 + wk*32 + jj*16 + lg*4 + r
#pragma unroll
    for (int jj = 0; jj < 2; ++jj) {
      f32x4 pv;
      u16x4 pb;
      if (full) {
#pragma unroll
        for (int r = 0; r < 4; ++r) {
          float p = __builtin_amdgcn_exp2f(fmaf(sa[jj][r], SC2_, off));
          pv[r] = p;
          pb[r] = f2b(p);
        }
      } else {
#pragma unroll
        for (int r = 0; r < 4; ++r) {
          int bit = jj * 16 + lg * 4 + r;
          float x = ((mw >> bit) & 1) ? fmaf(sa[jj][r], SC2_, off) : -3.0e9f;
          float p = __builtin_amdgcn_exp2f(x);
          pv[r] = p;
          pb[r] = f2b(p);
        }
      }
      // streaming store: bypass L2 so K/V stay resident
      __builtin_nontemporal_store(pv,
          (f32x4*)&wrow[k0 + wk * 32 + jj * 16 + lg * 4]);
      *(u16x4*)&Psw[lr * 72 + wk * 32 + jj * 16 + lg * 4] = pb;
    }

    // PV over this wave's 32-sk slice: A = P (row=sq), B = V^T (col=hd)
    bf16x8 pa = asb(*(const u16x8*)&Psw[lr * 72 + wk * 32 + lk]);
#pragma unroll
    for (int j2 = 0; j2 < 4; ++j2) {
      bf16x8 vf = asb(*(const u16x8*)&Vs[(j2 * 16 + lr) * 72 + wk * 32 + lk]);
      oacc[j2] = __builtin_amdgcn_mfma_f32_16x16x32_bf16(pa, vf, oacc[j2], 0, 0, 0);
    }
  }

  // combine sk-half partials: wave (wq,1) -> LDS, wave (wq,0) adds + stores
  __syncthreads();                      // all tile LDS reads done; overlay safe
  const int ci = (wq * 64 + lane) * 17; // 17-dword stride: conflict-free
  if (wk == 1) {
#pragma unroll
    for (int j2 = 0; j2 < 4; ++j2)
#pragma unroll
      for (int r = 0; r < 4; ++r) cs[ci + j2 * 4 + r] = oacc[j2][r];
  }
  __syncthreads();
  if (wk == 0) {
    // D: col = hd = j2*16+lr, row = sq-local = lg*4+r
#pragma unroll
    for (int j2 = 0; j2 < 4; ++j2)
#pragma unroll
      for (int r = 0; r < 4; ++r) {
        float v = oacc[j2][r] + cs[ci + j2 * 4 + r];
        attn_out[((size_t)b * S_ + q0 + wq * 16 + lg * 4 + r) * D_ + h * HD_ + j2 * 16 + lr] =
            f2b(v);
      }
  }
}

// ---------------- launch ----------------
extern "C" void kernel_launch(void* const* d_in, const int* in_sizes, int n_in,
                              void* d_out, int out_size, void* d_ws, size_t ws_size,
                              hipStream_t stream) {
  const float* query = (const float*)d_in[0];
  const float* key   = (const float*)d_in[1];
  const float* value = (const float*)d_in[2];
  const int*   mask  = (const int*)d_in[3];
  const float* Wq = (const float*)d_in[4];
  const float* bq = (const float*)d_in[5];
  const float* Wk = (const float*)d_in[6];
  const float* bk = (const float*)d_in[7];
  const float* Wv = (const float*)d_in[8];
  const float* bv = (const float*)d_in[9];
  const float* Wo = (const float*)d_in[10];
  const float* bo = (const float*)d_in[11];

  const int NE = B_ * S_ * D_;   // 4194304
  const int NW = D_ * D_;        // 1048576

  char* ws = (char*)d_ws;
  unsigned short* xin  = (unsigned short*)(ws);              // 3*NE bf16, dead after proj
  uint32_t*       mbits = (uint32_t*)(ws + 8388608);         // 1MB, inside dead xin
  unsigned short* wbuf = (unsigned short*)(ws + 25165824);   // 4*NW bf16
  unsigned short* qkv  = (unsigned short*)(ws + 33554432);   // 3*NE bf16 (v stored ^T)
  unsigned short* aout = (unsigned short*)(ws + 59244544);   // NE bf16

  cast3<<<dim3(NE / 2048, 3), dim3(256), 0, stream>>>(query, key, value, xin, NE);
  cast4<<<dim3(NW / 2048, 4), dim3(256), 0, stream>>>(Wq, Wk, Wv, Wo, wbuf, NW);

  // q,k,v projections (z = 0,1,2); z==2 writes V transposed per head
  gemm_bt<0><<<dim3(32, 8, 3), dim3(256), 0, stream>>>(
      xin, wbuf, bq, bk, bv, qkv, 4096, 1024, 1024);

  // xin dead now: build mask bits there
  pack_mask<<<dim3(B_ * S_ * S_ / 256), dim3(256), 0, stream>>>(mask, mbits);

  float* w_out = (float*)d_out + NE;   // attn_weights region
  attn_fused<<<dim3(32, 32), dim3(512), 0, stream>>>(
      qkv, qkv + NE, qkv + 2 * NE, mbits, w_out, aout);

  // output projection -> fp32 d_out
  gemm_bt<1><<<dim3(32, 8, 1), dim3(256), 0, stream>>>(
      aout, wbuf + 3 * NW, bo, bo, bo, d_out, 4096, 1024, 1024);
}

// Round 16
// 272.391 us; speedup vs baseline: 1.1314x; 1.0377x over previous
//
#include <hip/hip_runtime.h>
#include <stdint.h>

#define B_ 2
#define S_ 2048
#define D_ 1024
#define H_ 16
#define HD_ 64
#define NT_ (S_ / 64)
// SCALE * log2(e): softmax computed in exp2 domain
#define SC2_ 0.18033688011112042f

typedef __bf16 bf16_t;
typedef bf16_t bf16x8 __attribute__((ext_vector_type(8)));
typedef float f32x4 __attribute__((ext_vector_type(4)));
typedef unsigned short u16x8 __attribute__((ext_vector_type(8)));
typedef unsigned short u16x4 __attribute__((ext_vector_type(4)));

static __device__ __forceinline__ unsigned short f2b(float f) {
  return __builtin_bit_cast(unsigned short, (bf16_t)f);   // native cvt (RNE)
}

static __device__ __forceinline__ bf16x8 asb(u16x8 u) {
  return __builtin_bit_cast(bf16x8, u);
}

// Soft barrier: order LDS ops only (lgkmcnt), do NOT drain vmcnt -- keeps
// register-prefetch global loads in flight across the barrier (T4 pattern).
// __syncthreads() would emit s_waitcnt vmcnt(0) and serialize prefetch
// latency into every tile.
static __device__ __forceinline__ void barrier_lds() {
  asm volatile("s_waitcnt lgkmcnt(0)" ::: "memory");
  __builtin_amdgcn_s_barrier();
}

// ---------------- cast fp32 -> bf16, fused launches ----------------
__global__ void cast3(const float* __restrict__ a, const float* __restrict__ b,
                      const float* __restrict__ c,
                      unsigned short* __restrict__ dst, int n) {
  const float* src = blockIdx.y == 0 ? a : (blockIdx.y == 1 ? b : c);
  unsigned short* d = dst + (size_t)blockIdx.y * n;
  int i = (blockIdx.x * blockDim.x + threadIdx.x) * 8;
  if (i >= n) return;
  float4 f0 = *(const float4*)(src + i);
  float4 f1 = *(const float4*)(src + i + 4);
  u16x8 o;
  o[0] = f2b(f0.x); o[1] = f2b(f0.y); o[2] = f2b(f0.z); o[3] = f2b(f0.w);
  o[4] = f2b(f1.x); o[5] = f2b(f1.y); o[6] = f2b(f1.z); o[7] = f2b(f1.w);
  *(u16x8*)(d + i) = o;
}

__global__ void cast4(const float* __restrict__ a, const float* __restrict__ b,
                      const float* __restrict__ c, const float* __restrict__ e,
                      unsigned short* __restrict__ dst, int n) {
  const float* src = blockIdx.y == 0 ? a
                   : (blockIdx.y == 1 ? b : (blockIdx.y == 2 ? c : e));
  unsigned short* d = dst + (size_t)blockIdx.y * n;
  int i = (blockIdx.x * blockDim.x + threadIdx.x) * 8;
  if (i >= n) return;
  float4 f0 = *(const float4*)(src + i);
  float4 f1 = *(const float4*)(src + i + 4);
  u16x8 o;
  o[0] = f2b(f0.x); o[1] = f2b(f0.y); o[2] = f2b(f0.z); o[3] = f2b(f0.w);
  o[4] = f2b(f1.x); o[5] = f2b(f1.y); o[6] = f2b(f1.z); o[7] = f2b(f1.w);
  *(u16x8*)(d + i) = o;
}

// ---------------- pack mask to bits via ballot ----------------
__global__ void pack_mask(const int* __restrict__ mask,
                          uint32_t* __restrict__ mbits) {
  int i = blockIdx.x * blockDim.x + threadIdx.x;
  unsigned long long bits = __ballot(mask[i] != 0);
  if ((threadIdx.x & 63) == 0)
    *(unsigned long long*)&mbits[i >> 5] = bits;
}

// ---------------- bf16 GEMM (r2 structure + soft barriers) ------------------
// Reg-staged + one-K-step prefetch + padded-40 LDS. Soft barriers keep the
// prefetch in flight across the K-loop barrier.
// OUTMODE 0: z=0,1 -> bf16 head-split [B,H,S,HD]; z=2 -> bf16 V^T [B,H,HD,S].
// OUTMODE 1: fp32 row-major [M,N] (non-temporal: never re-read).
template<int OUTMODE>
__global__ __launch_bounds__(256)
void gemm_bt(const unsigned short* __restrict__ Ab,
             const unsigned short* __restrict__ Wb,
             const float* __restrict__ bq_,
             const float* __restrict__ bk_,
             const float* __restrict__ bv_,
             void* __restrict__ outv,
             int M, int N, int K) {
  const int z = blockIdx.z;
  const unsigned short* A = Ab + (size_t)z * M * K;
  const unsigned short* W = Wb + (size_t)z * N * K;
  const float* bias = z == 0 ? bq_ : (z == 1 ? bk_ : bv_);

  // padded stride 40 u16 = 80B (5 mod 8 -> 2-way bank spread on b128 reads)
  __shared__ __align__(16) unsigned short As[128 * 40];
  __shared__ __align__(16) unsigned short Bs[128 * 40];

  const int tid = threadIdx.x;
  const int lane = tid & 63;
  const int wave = tid >> 6;
  const int wm = wave >> 1, wn = wave & 1;
  const int row0 = blockIdx.x * 128;
  const int col0 = blockIdx.y * 128;

  const int srow = tid >> 2;        // 0..63
  const int scol = (tid & 3) * 8;   // 0,8,16,24
  const int lr = lane & 15;
  const int lg = lane >> 4;
  const int lk = lg * 8;

  f32x4 acc[4][4] = {};

  u16x8 a0 = *(const u16x8*)&A[(size_t)(row0 + srow) * K + scol];
  u16x8 a1 = *(const u16x8*)&A[(size_t)(row0 + srow + 64) * K + scol];
  u16x8 b0 = *(const u16x8*)&W[(size_t)(col0 + srow) * K + scol];
  u16x8 b1 = *(const u16x8*)&W[(size_t)(col0 + srow + 64) * K + scol];

  for (int k0 = 0; k0 < K; k0 += 32) {
    barrier_lds();   // prior iteration's LDS reads complete
    *(u16x8*)&As[srow * 40 + scol] = a0;
    *(u16x8*)&As[(srow + 64) * 40 + scol] = a1;
    *(u16x8*)&Bs[srow * 40 + scol] = b0;
    *(u16x8*)&Bs[(srow + 64) * 40 + scol] = b1;
    if (k0 + 32 < K) {
      a0 = *(const u16x8*)&A[(size_t)(row0 + srow) * K + k0 + 32 + scol];
      a1 = *(const u16x8*)&A[(size_t)(row0 + srow + 64) * K + k0 + 32 + scol];
      b0 = *(const u16x8*)&W[(size_t)(col0 + srow) * K + k0 + 32 + scol];
      b1 = *(const u16x8*)&W[(size_t)(col0 + srow + 64) * K + k0 + 32 + scol];
    }
    barrier_lds();   // LDS writes visible; prefetch stays in flight

    bf16x8 af[4], bfr[4];
#pragma unroll
    for (int i = 0; i < 4; ++i)
      af[i] = asb(*(const u16x8*)&As[(wm * 64 + i * 16 + lr) * 40 + lk]);
#pragma unroll
    for (int j = 0; j < 4; ++j)
      bfr[j] = asb(*(const u16x8*)&Bs[(wn * 64 + j * 16 + lr) * 40 + lk]);
#pragma unroll
    for (int i = 0; i < 4; ++i)
#pragma unroll
      for (int j = 0; j < 4; ++j)
        acc[i][j] = __builtin_amdgcn_mfma_f32_16x16x32_bf16(af[i], bfr[j], acc[i][j], 0, 0, 0);
  }

  const size_t zo = (size_t)z * M * N;
#pragma unroll
  for (int i = 0; i < 4; ++i) {
#pragma unroll
    for (int j = 0; j < 4; ++j) {
      const int row_ = row0 + wm * 64 + i * 16 + lg * 4;
      const int col = col0 + wn * 64 + j * 16 + lr;
      const float bcol = bias[col];
      if (OUTMODE == 1) {
        float* O = (float*)outv;
#pragma unroll
        for (int r = 0; r < 4; ++r)
          __builtin_nontemporal_store(acc[i][j][r] + bcol,
                                      &O[(size_t)(row_ + r) * N + col]);
      } else if (z == 2) {
        // V^T: [bh][hd][s], 4 consecutive s per lane -> 8B store
        unsigned short* O = (unsigned short*)outv + zo;
        int b = row_ >> 11, s = row_ & 2047;
        int h = col >> 6, hd = col & 63;
        u16x4 pk;
#pragma unroll
        for (int r = 0; r < 4; ++r) pk[r] = f2b(acc[i][j][r] + bcol);
        *(u16x4*)&O[(((size_t)b * H_ + h) * HD_ + hd) * S_ + s] = pk;
      } else {
        unsigned short* O = (unsigned short*)outv + zo;
        int h = col >> 6, hd = col & 63;
#pragma unroll
        for (int r = 0; r < 4; ++r) {
          int row = row_ + r;
          int b = row >> 11, s = row & 2047;
          O[(((size_t)b * H_ + h) * S_ + s) * HD_ + hd] = f2b(acc[i][j][r] + bcol);
        }
      }
    }
  }
}

// XCD-aware remap for grid (32,32): each XCD owns 4 consecutive bh values so
// its private L2 keeps those heads' K/V/Q resident across all q-tiles.
static __device__ __forceinline__ void xcd_map(int& bh, int& qt) {
  int lin = blockIdx.y * 32 + blockIdx.x;
  int xcd = lin & 7, k = lin >> 3;          // 128 blocks per XCD
  bh = (xcd << 2) | (k >> 5);               // 4 heads per XCD
  qt = k & 31;
}

// ---------------- fused attention (r15 + soft barriers) ----------------------
// 64 q-rows per block, 8 waves = 4 q-subtiles x 2 sk-halves.
// Loop 1: per-row (m2,l) with KVBLK=128. Merge via LDS. Loop 2: KVBLK=64
// weights write (nt) + PV. All barriers are lgkmcnt-only soft barriers.
__global__ __launch_bounds__(512)
void attn_fused(const unsigned short* __restrict__ q_bh,
                const unsigned short* __restrict__ k_bh,
                const unsigned short* __restrict__ vt_g,
                const uint32_t* __restrict__ mbits,
                float* __restrict__ w_out,
                unsigned short* __restrict__ attn_out) {
  int bh, qt;
  xcd_map(bh, qt);
  const int b = bh >> 4, h = bh & (H_ - 1);
  const int q0 = qt * 64;

  __shared__ __align__(16) unsigned char smem[36864];
  unsigned short* Ks = (unsigned short*)smem;        // [64*72]  9216B
  unsigned short* Vs = Ks + 64 * 72;                 // [64*72]  9216B
  unsigned short* Kbig = Ks;                         // loop1: [128*72] 18432B
  unsigned short* Ps = Vs + 64 * 72;                 // [8][16*72] 18432B
  float* cs = (float*)smem;                          // end-overlay, 17408B
  float2* mls = (float2*)Ps;                         // merge overlay, 1KB

  const int tid = threadIdx.x, lane = tid & 63, w = tid >> 6;
  const int wq = w >> 1, wk = w & 1;
  const int srow = tid >> 3, scol = (tid & 7) * 8;   // srow 0..63
  const int lr = lane & 15, lg = lane >> 4, lk = lg * 8;
  const int sq = q0 + wq * 16 + lr;
  unsigned short* Psw = Ps + w * (16 * 72);

  const unsigned short* qb = q_bh + ((size_t)bh * S_ + sq) * HD_;
  bf16x8 qf0 = asb(*(const u16x8*)&qb[lk]);
  bf16x8 qf1 = asb(*(const u16x8*)&qb[32 + lk]);

  const uint32_t* mrow = mbits + ((size_t)b * S_ + sq) * (S_ / 32);
  const unsigned short* kb = k_bh + (size_t)bh * S_ * HD_;
  const unsigned short* vb = vt_g + (size_t)bh * HD_ * S_;

  // ------- loop 1: per-row (m2, l); KVBLK=128, wave owns rows wk*64.. -------
  float m2 = -__builtin_inff(), l = 0.f;
  {
    u16x8 t0 = *(const u16x8*)&kb[srow * 64 + scol];
    u16x8 t1 = *(const u16x8*)&kb[(srow + 64) * 64 + scol];
    for (int kt = 0; kt < S_ / 128; ++kt) {
      barrier_lds();
      *(u16x8*)&Kbig[srow * 72 + scol] = t0;
      *(u16x8*)&Kbig[(srow + 64) * 72 + scol] = t1;
      if (kt + 1 < S_ / 128) {
        t0 = *(const u16x8*)&kb[((kt + 1) * 128 + srow) * 64 + scol];
        t1 = *(const u16x8*)&kb[((kt + 1) * 128 + 64 + srow) * 64 + scol];
      }
      barrier_lds();

      uint2 mw = *(const uint2*)&mrow[kt * 4 + wk * 2];
      const bool full = __all((mw.x & mw.y) == 0xffffffffu);

      f32x4 sa[4] = {};
#pragma unroll
      for (int j = 0; j < 4; ++j) {
        const int row = wk * 64 + j * 16 + lr;
        bf16x8 kf0 = asb(*(const u16x8*)&Kbig[row * 72 + lk]);
        bf16x8 kf1 = asb(*(const u16x8*)&Kbig[row * 72 + 32 + lk]);
        sa[j] = __builtin_amdgcn_mfma_f32_16x16x32_bf16(kf0, qf0, sa[j], 0, 0, 0);
        sa[j] = __builtin_amdgcn_mfma_f32_16x16x32_bf16(kf1, qf1, sa[j], 0, 0, 0);
      }

      float sv[4][4];
      if (full) {
#pragma unroll
        for (int j = 0; j < 4; ++j)
#pragma unroll
          for (int r = 0; r < 4; ++r) sv[j][r] = sa[j][r] * SC2_;
      } else {
#pragma unroll
        for (int j = 0; j < 4; ++j) {
          uint32_t mwj = (j < 2) ? mw.x : mw.y;
#pragma unroll
          for (int r = 0; r < 4; ++r) {
            int bit = (j & 1) * 16 + lg * 4 + r;
            sv[j][r] = ((mwj >> bit) & 1) ? sa[j][r] * SC2_ : -3.0e9f;
          }
        }
      }
      float tm = sv[0][0];
#pragma unroll
      for (int j = 0; j < 4; ++j)
#pragma unroll
        for (int r = 0; r < 4; ++r) tm = fmaxf(tm, sv[j][r]);
      tm = fmaxf(tm, __shfl_xor(tm, 16));
      tm = fmaxf(tm, __shfl_xor(tm, 32));
      float mnew = fmaxf(m2, tm);
      float ss = 0.f;
#pragma unroll
      for (int j = 0; j < 4; ++j)
#pragma unroll
        for (int r = 0; r < 4; ++r)
          ss += __builtin_amdgcn_exp2f(sv[j][r] - mnew);
      ss += __shfl_xor(ss, 16);
      ss += __shfl_xor(ss, 32);
      l = l * __builtin_amdgcn_exp2f(m2 - mnew) + ss;
      m2 = mnew;
    }
  }

  // ---------------- merge sk-halves: all lanes get full-row (m, l) ---------
  barrier_lds();                          // Kbig reads done; Ps idle -> overlay
  if (lg == 0) mls[wk * 64 + wq * 16 + lr] = make_float2(m2, l);
  barrier_lds();
  float2 h0 = mls[wq * 16 + lr];
  float2 h1 = mls[64 + wq * 16 + lr];
  const float mn = fmaxf(h0.x, h1.x);
  const float lsum = h0.y * __builtin_amdgcn_exp2f(h0.x - mn) +
                     h1.y * __builtin_amdgcn_exp2f(h1.x - mn);
  // p = exp2(sa*SC2 + off), off = -m - log2(l)  (normalization folded in)
  const float off = -mn - __builtin_amdgcn_logf(lsum);
  float* wrow = w_out + ((size_t)bh * S_ + sq) * S_;

  // ---------------- loop 2: weights write + PV ------------------------------
  u16x8 t0 = *(const u16x8*)&kb[srow * 64 + scol];
  u16x8 v0 = *(const u16x8*)&vb[(size_t)srow * S_ + scol];

  f32x4 oacc[4] = {};

  for (int kt = 0; kt < NT_; ++kt) {
    const int k0 = kt * 64;
    barrier_lds();   // prior iteration's QK/PV LDS reads (or mls reads) done
    *(u16x8*)&Ks[srow * 72 + scol] = t0;
    *(u16x8*)&Vs[srow * 72 + scol] = v0;
    if (kt + 1 < NT_) {
      t0 = *(const u16x8*)&kb[(k0 + 64 + srow) * 64 + scol];
      v0 = *(const u16x8*)&vb[(size_t)srow * S_ + k0 + 64 + scol];
    }
    barrier_lds();   // LDS writes visible; prefetch stays in flight

    uint32_t mw = mrow[kt * 2 + wk];
    const bool full = __all(mw == 0xffffffffu);

    f32x4 sa[2] = {};
#pragma unroll
    for (int jj = 0; jj < 2; ++jj) {
      const int j = wk * 2 + jj;
      bf16x8 kf0 = asb(*(const u16x8*)&Ks[(j * 16 + lr) * 72 + lk]);
      bf16x8 kf1 = asb(*(const u16x8*)&Ks[(j * 16 + lr) * 72 + 32 + lk]);
      sa[jj] = __builtin_amdgcn_mfma_f32_16x16x32_bf16(kf0, qf0, sa[jj], 0, 0, 0);
      sa[jj] = __builtin_amdgcn_mfma_f32_16x16x32_bf16(kf1, qf1, sa[jj], 0, 0, 0);
    }

    // weights: lane owns row sq; sk = k0 + wk*32 + jj*16 + lg*4 + r
#pragma unroll
    for (int jj = 0; jj < 2; ++jj) {
      f32x4 pv;
      u16x4 pb;
      if (full) {
#pragma unroll
        for (int r = 0; r < 4; ++r) {
          float p = __builtin_amdgcn_exp2f(fmaf(sa[jj][r], SC2_, off));
          pv[r] = p;
          pb[r] = f2b(p);
        }
      } else {
#pragma unroll
        for (int r = 0; r < 4; ++r) {
          int bit = jj * 16 + lg * 4 + r;
          float x = ((mw >> bit) & 1) ? fmaf(sa[jj][r], SC2_, off) : -3.0e9f;
          float p = __builtin_amdgcn_exp2f(x);
          pv[r] = p;
          pb[r] = f2b(p);
        }
      }
      // streaming store: bypass L2 so K/V stay resident
      __builtin_nontemporal_store(pv,
          (f32x4*)&wrow[k0 + wk * 32 + jj * 16 + lg * 4]);
      *(u16x4*)&Psw[lr * 72 + wk * 32 + jj * 16 + lg * 4] = pb;
    }

    // PV over this wave's 32-sk slice: A = P (row=sq), B = V^T (col=hd)
    bf16x8 pa = asb(*(const u16x8*)&Psw[lr * 72 + wk * 32 + lk]);
#pragma unroll
    for (int j2 = 0; j2 < 4; ++j2) {
      bf16x8 vf = asb(*(const u16x8*)&Vs[(j2 * 16 + lr) * 72 + wk * 32 + lk]);
      oacc[j2] = __builtin_amdgcn_mfma_f32_16x16x32_bf16(pa, vf, oacc[j2], 0, 0, 0);
    }
  }

  // combine sk-half partials: wave (wq,1) -> LDS, wave (wq,0) adds + stores
  barrier_lds();                        // all tile LDS reads done; overlay safe
  const int ci = (wq * 64 + lane) * 17; // 17-dword stride: conflict-free
  if (wk == 1) {
#pragma unroll
    for (int j2 = 0; j2 < 4; ++j2)
#pragma unroll
      for (int r = 0; r < 4; ++r) cs[ci + j2 * 4 + r] = oacc[j2][r];
  }
  barrier_lds();
  if (wk == 0) {
    // D: col = hd = j2*16+lr, row = sq-local = lg*4+r
#pragma unroll
    for (int j2 = 0; j2 < 4; ++j2)
#pragma unroll
      for (int r = 0; r < 4; ++r) {
        float v = oacc[j2][r] + cs[ci + j2 * 4 + r];
        attn_out[((size_t)b * S_ + q0 + wq * 16 + lg * 4 + r) * D_ + h * HD_ + j2 * 16 + lr] =
            f2b(v);
      }
  }
}

// ---------------- launch ----------------
extern "C" void kernel_launch(void* const* d_in, const int* in_sizes, int n_in,
                              void* d_out, int out_size, void* d_ws, size_t ws_size,
                              hipStream_t stream) {
  const float* query = (const float*)d_in[0];
  const float* key   = (const float*)d_in[1];
  const float* value = (const float*)d_in[2];
  const int*   mask  = (const int*)d_in[3];
  const float* Wq = (const float*)d_in[4];
  const float* bq = (const float*)d_in[5];
  const float* Wk = (const float*)d_in[6];
  const float* bk = (const float*)d_in[7];
  const float* Wv = (const float*)d_in[8];
  const float* bv = (const float*)d_in[9];
  const float* Wo = (const float*)d_in[10];
  const float* bo = (const float*)d_in[11];

  const int NE = B_ * S_ * D_;   // 4194304
  const int NW = D_ * D_;        // 1048576

  char* ws = (char*)d_ws;
  unsigned short* xin  = (unsigned short*)(ws);              // 3*NE bf16, dead after proj
  uint32_t*       mbits = (uint32_t*)(ws + 8388608);         // 1MB, inside dead xin
  unsigned short* wbuf = (unsigned short*)(ws + 25165824);   // 4*NW bf16
  unsigned short* qkv  = (unsigned short*)(ws + 33554432);   // 3*NE bf16 (v stored ^T)
  unsigned short* aout = (unsigned short*)(ws + 59244544);   // NE bf16

  cast3<<<dim3(NE / 2048, 3), dim3(256), 0, stream>>>(query, key, value, xin, NE);
  cast4<<<dim3(NW / 2048, 4), dim3(256), 0, stream>>>(Wq, Wk, Wv, Wo, wbuf, NW);

  // q,k,v projections (z = 0,1,2); z==2 writes V transposed per head
  gemm_bt<0><<<dim3(32, 8, 3), dim3(256), 0, stream>>>(
      xin, wbuf, bq, bk, bv, qkv, 4096, 1024, 1024);

  // xin dead now: build mask bits there
  pack_mask<<<dim3(B_ * S_ * S_ / 256), dim3(256), 0, stream>>>(mask, mbits);

  float* w_out = (float*)d_out + NE;   // attn_weights region
  attn_fused<<<dim3(32, 32), dim3(512), 0, stream>>>(
      qkv, qkv + NE, qkv + 2 * NE, mbits, w_out, aout);

  // output projection -> fp32 d_out
  gemm_bt<1><<<dim3(32, 8, 1), dim3(256), 0, stream>>>(
      aout, wbuf + 3 * NW, bo, bo, bo, d_out, 4096, 1024, 1024);
}

// Round 17
// 270.807 us; speedup vs baseline: 1.1380x; 1.0058x over previous
//
#include <hip/hip_runtime.h>
#include <stdint.h>

#define B_ 2
#define S_ 2048
#define D_ 1024
#define H_ 16
#define HD_ 64
#define NT_ (S_ / 64)
// SCALE * log2(e): softmax computed in exp2 domain
#define SC2_ 0.18033688011112042f

typedef __bf16 bf16_t;
typedef bf16_t bf16x8 __attribute__((ext_vector_type(8)));
typedef float f32x4 __attribute__((ext_vector_type(4)));
typedef unsigned short u16x8 __attribute__((ext_vector_type(8)));
typedef unsigned short u16x4 __attribute__((ext_vector_type(4)));

static __device__ __forceinline__ unsigned short f2b(float f) {
  return __builtin_bit_cast(unsigned short, (bf16_t)f);   // native cvt (RNE)
}

static __device__ __forceinline__ bf16x8 asb(u16x8 u) {
  return __builtin_bit_cast(bf16x8, u);
}

// Soft barrier: order LDS ops only (lgkmcnt), do NOT drain vmcnt -- keeps
// register-prefetch global loads in flight across the barrier (T4 pattern).
static __device__ __forceinline__ void barrier_lds() {
  asm volatile("s_waitcnt lgkmcnt(0)" ::: "memory");
  __builtin_amdgcn_s_barrier();
}

// ---------------- fused cast fp32 -> bf16 (7 segments, one launch) ----------
__global__ void cast7(const float* __restrict__ q, const float* __restrict__ k,
                      const float* __restrict__ v, const float* __restrict__ wq,
                      const float* __restrict__ wk, const float* __restrict__ wv,
                      const float* __restrict__ wo,
                      unsigned short* __restrict__ xin,
                      unsigned short* __restrict__ wbuf,
                      int ne, int nw) {
  const int y = blockIdx.y;
  const float* src;
  unsigned short* d;
  int n;
  if (y < 3) {
    src = y == 0 ? q : (y == 1 ? k : v);
    d = xin + (size_t)y * ne;
    n = ne;
  } else {
    src = y == 3 ? wq : (y == 4 ? wk : (y == 5 ? wv : wo));
    d = wbuf + (size_t)(y - 3) * nw;
    n = nw;
  }
  int i = (blockIdx.x * blockDim.x + threadIdx.x) * 8;
  if (i >= n) return;
  float4 f0 = *(const float4*)(src + i);
  float4 f1 = *(const float4*)(src + i + 4);
  u16x8 o;
  o[0] = f2b(f0.x); o[1] = f2b(f0.y); o[2] = f2b(f0.z); o[3] = f2b(f0.w);
  o[4] = f2b(f1.x); o[5] = f2b(f1.y); o[6] = f2b(f1.z); o[7] = f2b(f1.w);
  *(u16x8*)(d + i) = o;
}

// ---------------- pack mask to bits via ballot ----------------
__global__ void pack_mask(const int* __restrict__ mask,
                          uint32_t* __restrict__ mbits) {
  int i = blockIdx.x * blockDim.x + threadIdx.x;
  unsigned long long bits = __ballot(mask[i] != 0);
  if ((threadIdx.x & 63) == 0)
    *(unsigned long long*)&mbits[i >> 5] = bits;
}

// ---------------- bf16 GEMM (r16: r2 structure + soft barriers) -------------
template<int OUTMODE>
__global__ __launch_bounds__(256)
void gemm_bt(const unsigned short* __restrict__ Ab,
             const unsigned short* __restrict__ Wb,
             const float* __restrict__ bq_,
             const float* __restrict__ bk_,
             const float* __restrict__ bv_,
             void* __restrict__ outv,
             int M, int N, int K) {
  const int z = blockIdx.z;
  const unsigned short* A = Ab + (size_t)z * M * K;
  const unsigned short* W = Wb + (size_t)z * N * K;
  const float* bias = z == 0 ? bq_ : (z == 1 ? bk_ : bv_);

  __shared__ __align__(16) unsigned short As[128 * 40];
  __shared__ __align__(16) unsigned short Bs[128 * 40];

  const int tid = threadIdx.x;
  const int lane = tid & 63;
  const int wave = tid >> 6;
  const int wm = wave >> 1, wn = wave & 1;
  const int row0 = blockIdx.x * 128;
  const int col0 = blockIdx.y * 128;

  const int srow = tid >> 2;
  const int scol = (tid & 3) * 8;
  const int lr = lane & 15;
  const int lg = lane >> 4;
  const int lk = lg * 8;

  f32x4 acc[4][4] = {};

  u16x8 a0 = *(const u16x8*)&A[(size_t)(row0 + srow) * K + scol];
  u16x8 a1 = *(const u16x8*)&A[(size_t)(row0 + srow + 64) * K + scol];
  u16x8 b0 = *(const u16x8*)&W[(size_t)(col0 + srow) * K + scol];
  u16x8 b1 = *(const u16x8*)&W[(size_t)(col0 + srow + 64) * K + scol];

  for (int k0 = 0; k0 < K; k0 += 32) {
    barrier_lds();
    *(u16x8*)&As[srow * 40 + scol] = a0;
    *(u16x8*)&As[(srow + 64) * 40 + scol] = a1;
    *(u16x8*)&Bs[srow * 40 + scol] = b0;
    *(u16x8*)&Bs[(srow + 64) * 40 + scol] = b1;
    if (k0 + 32 < K) {
      a0 = *(const u16x8*)&A[(size_t)(row0 + srow) * K + k0 + 32 + scol];
      a1 = *(const u16x8*)&A[(size_t)(row0 + srow + 64) * K + k0 + 32 + scol];
      b0 = *(const u16x8*)&W[(size_t)(col0 + srow) * K + k0 + 32 + scol];
      b1 = *(const u16x8*)&W[(size_t)(col0 + srow + 64) * K + k0 + 32 + scol];
    }
    barrier_lds();

    bf16x8 af[4], bfr[4];
#pragma unroll
    for (int i = 0; i < 4; ++i)
      af[i] = asb(*(const u16x8*)&As[(wm * 64 + i * 16 + lr) * 40 + lk]);
#pragma unroll
    for (int j = 0; j < 4; ++j)
      bfr[j] = asb(*(const u16x8*)&Bs[(wn * 64 + j * 16 + lr) * 40 + lk]);
#pragma unroll
    for (int i = 0; i < 4; ++i)
#pragma unroll
      for (int j = 0; j < 4; ++j)
        acc[i][j] = __builtin_amdgcn_mfma_f32_16x16x32_bf16(af[i], bfr[j], acc[i][j], 0, 0, 0);
  }

  const size_t zo = (size_t)z * M * N;
#pragma unroll
  for (int i = 0; i < 4; ++i) {
#pragma unroll
    for (int j = 0; j < 4; ++j) {
      const int row_ = row0 + wm * 64 + i * 16 + lg * 4;
      const int col = col0 + wn * 64 + j * 16 + lr;
      const float bcol = bias[col];
      if (OUTMODE == 1) {
        float* O = (float*)outv;
#pragma unroll
        for (int r = 0; r < 4; ++r)
          __builtin_nontemporal_store(acc[i][j][r] + bcol,
                                      &O[(size_t)(row_ + r) * N + col]);
      } else if (z == 2) {
        unsigned short* O = (unsigned short*)outv + zo;
        int b = row_ >> 11, s = row_ & 2047;
        int h = col >> 6, hd = col & 63;
        u16x4 pk;
#pragma unroll
        for (int r = 0; r < 4; ++r) pk[r] = f2b(acc[i][j][r] + bcol);
        *(u16x4*)&O[(((size_t)b * H_ + h) * HD_ + hd) * S_ + s] = pk;
      } else {
        unsigned short* O = (unsigned short*)outv + zo;
        int h = col >> 6, hd = col & 63;
#pragma unroll
        for (int r = 0; r < 4; ++r) {
          int row = row_ + r;
          int b = row >> 11, s = row & 2047;
          O[(((size_t)b * H_ + h) * S_ + s) * HD_ + hd] = f2b(acc[i][j][r] + bcol);
        }
      }
    }
  }
}

// XCD-aware remap for grid (32,32)
static __device__ __forceinline__ void xcd_map(int& bh, int& qt) {
  int lin = blockIdx.y * 32 + blockIdx.x;
  int xcd = lin & 7, k = lin >> 3;
  bh = (xcd << 2) | (k >> 5);
  qt = k & 31;
}

// ---------------- fused attention (r16 + loop2 KVBLK=128) --------------------
// 64 q-rows per block, 8 waves = 4 q-subtiles x 2 sk-halves.
// Loop 1: (m2,l) with KVBLK=128 (unchanged from r16).
// Loop 2: KVBLK=128, 16 iterations -- K[128x72] + V^T[64x136] staged per iter;
// each wave processes its 64-col half as two 32-col sub-steps reusing a
// compact wave-private Ps (16x36). Soft barriers throughout.
__global__ __launch_bounds__(512)
void attn_fused(const unsigned short* __restrict__ q_bh,
                const unsigned short* __restrict__ k_bh,
                const unsigned short* __restrict__ vt_g,
                const uint32_t* __restrict__ mbits,
                float* __restrict__ w_out,
                unsigned short* __restrict__ attn_out) {
  int bh, qt;
  xcd_map(bh, qt);
  const int b = bh >> 4, h = bh & (H_ - 1);
  const int q0 = qt * 64;

  __shared__ __align__(16) unsigned char smem[45056];
  unsigned short* Ks = (unsigned short*)smem;          // [128*72] 18432B
  unsigned short* Vs = Ks + 128 * 72;                  // [64*136] 17408B
  unsigned short* Ps = Vs + 64 * 136;                  // [8][16*36] 9216B
  unsigned short* Kbig = Ks;                           // loop1: [128*72]
  float* cs = (float*)smem;                            // end-overlay 17408B
  float2* mls = (float2*)Ps;                           // merge overlay 1KB

  const int tid = threadIdx.x, lane = tid & 63, w = tid >> 6;
  const int wq = w >> 1, wk = w & 1;
  const int srow = tid >> 3, scol = (tid & 7) * 8;     // srow 0..63
  const int lr = lane & 15, lg = lane >> 4, lk = lg * 8;
  const int sq = q0 + wq * 16 + lr;
  unsigned short* Psw = Ps + w * (16 * 36);

  const unsigned short* qb = q_bh + ((size_t)bh * S_ + sq) * HD_;
  bf16x8 qf0 = asb(*(const u16x8*)&qb[lk]);
  bf16x8 qf1 = asb(*(const u16x8*)&qb[32 + lk]);

  const uint32_t* mrow = mbits + ((size_t)b * S_ + sq) * (S_ / 32);
  const unsigned short* kb = k_bh + (size_t)bh * S_ * HD_;
  const unsigned short* vb = vt_g + (size_t)bh * HD_ * S_;

  // ------- loop 1: per-row (m2, l); KVBLK=128 (r16 structure) --------------
  float m2 = -__builtin_inff(), l = 0.f;
  {
    u16x8 t0 = *(const u16x8*)&kb[srow * 64 + scol];
    u16x8 t1 = *(const u16x8*)&kb[(srow + 64) * 64 + scol];
    for (int kt = 0; kt < S_ / 128; ++kt) {
      barrier_lds();
      *(u16x8*)&Kbig[srow * 72 + scol] = t0;
      *(u16x8*)&Kbig[(srow + 64) * 72 + scol] = t1;
      if (kt + 1 < S_ / 128) {
        t0 = *(const u16x8*)&kb[((kt + 1) * 128 + srow) * 64 + scol];
        t1 = *(const u16x8*)&kb[((kt + 1) * 128 + 64 + srow) * 64 + scol];
      }
      barrier_lds();

      uint2 mw = *(const uint2*)&mrow[kt * 4 + wk * 2];
      const bool full = __all((mw.x & mw.y) == 0xffffffffu);

      f32x4 sa[4] = {};
#pragma unroll
      for (int j = 0; j < 4; ++j) {
        const int row = wk * 64 + j * 16 + lr;
        bf16x8 kf0 = asb(*(const u16x8*)&Kbig[row * 72 + lk]);
        bf16x8 kf1 = asb(*(const u16x8*)&Kbig[row * 72 + 32 + lk]);
        sa[j] = __builtin_amdgcn_mfma_f32_16x16x32_bf16(kf0, qf0, sa[j], 0, 0, 0);
        sa[j] = __builtin_amdgcn_mfma_f32_16x16x32_bf16(kf1, qf1, sa[j], 0, 0, 0);
      }

      float sv[4][4];
      if (full) {
#pragma unroll
        for (int j = 0; j < 4; ++j)
#pragma unroll
          for (int r = 0; r < 4; ++r) sv[j][r] = sa[j][r] * SC2_;
      } else {
#pragma unroll
        for (int j = 0; j < 4; ++j) {
          uint32_t mwj = (j < 2) ? mw.x : mw.y;
#pragma unroll
          for (int r = 0; r < 4; ++r) {
            int bit = (j & 1) * 16 + lg * 4 + r;
            sv[j][r] = ((mwj >> bit) & 1) ? sa[j][r] * SC2_ : -3.0e9f;
          }
        }
      }
      float tm = sv[0][0];
#pragma unroll
      for (int j = 0; j < 4; ++j)
#pragma unroll
        for (int r = 0; r < 4; ++r) tm = fmaxf(tm, sv[j][r]);
      tm = fmaxf(tm, __shfl_xor(tm, 16));
      tm = fmaxf(tm, __shfl_xor(tm, 32));
      float mnew = fmaxf(m2, tm);
      float ss = 0.f;
#pragma unroll
      for (int j = 0; j < 4; ++j)
#pragma unroll
        for (int r = 0; r < 4; ++r)
          ss += __builtin_amdgcn_exp2f(sv[j][r] - mnew);
      ss += __shfl_xor(ss, 16);
      ss += __shfl_xor(ss, 32);
      l = l * __builtin_amdgcn_exp2f(m2 - mnew) + ss;
      m2 = mnew;
    }
  }

  // ---------------- merge sk-halves ----------------------------------------
  barrier_lds();
  if (lg == 0) mls[wk * 64 + wq * 16 + lr] = make_float2(m2, l);
  barrier_lds();
  float2 h0 = mls[wq * 16 + lr];
  float2 h1 = mls[64 + wq * 16 + lr];
  const float mn = fmaxf(h0.x, h1.x);
  const float lsum = h0.y * __builtin_amdgcn_exp2f(h0.x - mn) +
                     h1.y * __builtin_amdgcn_exp2f(h1.x - mn);
  const float off = -mn - __builtin_amdgcn_logf(lsum);
  float* wrow = w_out + ((size_t)bh * S_ + sq) * S_;

  // ---------------- loop 2: KVBLK=128, weights write + PV -------------------
  // Staging per iter: K rows srow, srow+64 (t0,t1); V^T row srow, col-halves
  // scol and scol+64 (v0,v1). 4 prefetch regs per thread.
  u16x8 t0 = *(const u16x8*)&kb[srow * 64 + scol];
  u16x8 t1 = *(const u16x8*)&kb[(srow + 64) * 64 + scol];
  u16x8 v0 = *(const u16x8*)&vb[(size_t)srow * S_ + scol];
  u16x8 v1 = *(const u16x8*)&vb[(size_t)srow * S_ + 64 + scol];

  f32x4 oacc[4] = {};

  for (int kt = 0; kt < S_ / 128; ++kt) {
    const int k0 = kt * 128;
    barrier_lds();   // prior iteration's LDS reads complete
    *(u16x8*)&Ks[srow * 72 + scol] = t0;
    *(u16x8*)&Ks[(srow + 64) * 72 + scol] = t1;
    *(u16x8*)&Vs[srow * 136 + scol] = v0;
    *(u16x8*)&Vs[srow * 136 + 64 + scol] = v1;
    if (kt + 1 < S_ / 128) {
      t0 = *(const u16x8*)&kb[(k0 + 128 + srow) * 64 + scol];
      t1 = *(const u16x8*)&kb[(k0 + 192 + srow) * 64 + scol];
      v0 = *(const u16x8*)&vb[(size_t)srow * S_ + k0 + 128 + scol];
      v1 = *(const u16x8*)&vb[(size_t)srow * S_ + k0 + 192 + scol];
    }
    barrier_lds();   // LDS visible; prefetch stays in flight

    // two 32-col sub-steps over this wave's 64-col half
#pragma unroll
    for (int sub = 0; sub < 2; ++sub) {
      const int cbase = wk * 64 + sub * 32;       // local col base in tile
      uint32_t mw = mrow[kt * 4 + wk * 2 + sub];
      const bool full = __all(mw == 0xffffffffu);

      f32x4 sa[2] = {};
#pragma unroll
      for (int jj = 0; jj < 2; ++jj) {
        const int row = cbase + jj * 16 + lr;
        bf16x8 kf0 = asb(*(const u16x8*)&Ks[row * 72 + lk]);
        bf16x8 kf1 = asb(*(const u16x8*)&Ks[row * 72 + 32 + lk]);
        sa[jj] = __builtin_amdgcn_mfma_f32_16x16x32_bf16(kf0, qf0, sa[jj], 0, 0, 0);
        sa[jj] = __builtin_amdgcn_mfma_f32_16x16x32_bf16(kf1, qf1, sa[jj], 0, 0, 0);
      }

#pragma unroll
      for (int jj = 0; jj < 2; ++jj) {
        f32x4 pv;
        u16x4 pb;
        if (full) {
#pragma unroll
          for (int r = 0; r < 4; ++r) {
            float p = __builtin_amdgcn_exp2f(fmaf(sa[jj][r], SC2_, off));
            pv[r] = p;
            pb[r] = f2b(p);
          }
        } else {
#pragma unroll
          for (int r = 0; r < 4; ++r) {
            int bit = jj * 16 + lg * 4 + r;
            float x = ((mw >> bit) & 1) ? fmaf(sa[jj][r], SC2_, off) : -3.0e9f;
            float p = __builtin_amdgcn_exp2f(x);
            pv[r] = p;
            pb[r] = f2b(p);
          }
        }
        __builtin_nontemporal_store(pv,
            (f32x4*)&wrow[k0 + cbase + jj * 16 + lg * 4]);
        *(u16x4*)&Psw[lr * 36 + jj * 16 + lg * 4] = pb;   // wave-private
      }

      // PV over this sub-step's 32-sk slice
      bf16x8 pa = asb(*(const u16x8*)&Psw[lr * 36 + lk]);
#pragma unroll
      for (int j2 = 0; j2 < 4; ++j2) {
        bf16x8 vf = asb(*(const u16x8*)&Vs[(j2 * 16 + lr) * 136 + cbase + lk]);
        oacc[j2] = __builtin_amdgcn_mfma_f32_16x16x32_bf16(pa, vf, oacc[j2], 0, 0, 0);
      }
    }
  }

  // combine sk-half partials
  barrier_lds();
  const int ci = (wq * 64 + lane) * 17;
  if (wk == 1) {
#pragma unroll
    for (int j2 = 0; j2 < 4; ++j2)
#pragma unroll
      for (int r = 0; r < 4; ++r) cs[ci + j2 * 4 + r] = oacc[j2][r];
  }
  barrier_lds();
  if (wk == 0) {
#pragma unroll
    for (int j2 = 0; j2 < 4; ++j2)
#pragma unroll
      for (int r = 0; r < 4; ++r) {
        float v = oacc[j2][r] + cs[ci + j2 * 4 + r];
        attn_out[((size_t)b * S_ + q0 + wq * 16 + lg * 4 + r) * D_ + h * HD_ + j2 * 16 + lr] =
            f2b(v);
      }
  }
}

// ---------------- launch ----------------
extern "C" void kernel_launch(void* const* d_in, const int* in_sizes, int n_in,
                              void* d_out, int out_size, void* d_ws, size_t ws_size,
                              hipStream_t stream) {
  const float* query = (const float*)d_in[0];
  const float* key   = (const float*)d_in[1];
  const float* value = (const float*)d_in[2];
  const int*   mask  = (const int*)d_in[3];
  const float* Wq = (const float*)d_in[4];
  const float* bq = (const float*)d_in[5];
  const float* Wk = (const float*)d_in[6];
  const float* bk = (const float*)d_in[7];
  const float* Wv = (const float*)d_in[8];
  const float* bv = (const float*)d_in[9];
  const float* Wo = (const float*)d_in[10];
  const float* bo = (const float*)d_in[11];

  const int NE = B_ * S_ * D_;   // 4194304
  const int NW = D_ * D_;        // 1048576

  char* ws = (char*)d_ws;
  unsigned short* xin  = (unsigned short*)(ws);              // 3*NE bf16, dead after proj
  uint32_t*       mbits = (uint32_t*)(ws + 8388608);         // 1MB, inside dead xin
  unsigned short* wbuf = (unsigned short*)(ws + 25165824);   // 4*NW bf16
  unsigned short* qkv  = (unsigned short*)(ws + 33554432);   // 3*NE bf16 (v stored ^T)
  unsigned short* aout = (unsigned short*)(ws + 59244544);   // NE bf16

  cast7<<<dim3(NE / 2048, 7), dim3(256), 0, stream>>>(
      query, key, value, Wq, Wk, Wv, Wo, xin, wbuf, NE, NW);

  // q,k,v projections (z = 0,1,2); z==2 writes V transposed per head
  gemm_bt<0><<<dim3(32, 8, 3), dim3(256), 0, stream>>>(
      xin, wbuf, bq, bk, bv, qkv, 4096, 1024, 1024);

  // xin dead now: build mask bits there
  pack_mask<<<dim3(B_ * S_ * S_ / 256), dim3(256), 0, stream>>>(mask, mbits);

  float* w_out = (float*)d_out + NE;   // attn_weights region
  attn_fused<<<dim3(32, 32), dim3(512), 0, stream>>>(
      qkv, qkv + NE, qkv + 2 * NE, mbits, w_out, aout);

  // output projection -> fp32 d_out
  gemm_bt<1><<<dim3(32, 8, 1), dim3(256), 0, stream>>>(
      aout, wbuf + 3 * NW, bo, bo, bo, d_out, 4096, 1024, 1024);
}